// Round 5
// baseline (158.220 us; speedup 1.0000x reference)
//
#include <hip/hip_runtime.h>
#include <hip/hip_bf16.h>
#include <hip/hip_fp16.h>

#define NTOK 2048
#define DDIM 512
#define NBATCH 8

using bf16x8 = __attribute__((ext_vector_type(8))) short;
using f32x4  = __attribute__((ext_vector_type(4))) float;

__device__ __forceinline__ short f2bf(float f) {
  __hip_bfloat16 h = __float2bfloat16(f);
  union { __hip_bfloat16 h; short s; } u; u.h = h;
  return u.s;
}

__device__ __forceinline__ float h2f(short s) {
  union { short s; __half h; } u; u.s = s;
  return __half2float(u.h);
}

__device__ __forceinline__ __half f2h(float f) { return __float2half(f); }

// fp32 -> bf16 pre-convert: each thread handles 8 floats -> one 16B bf16x8 store.
__global__ __launch_bounds__(256) void convert_kernel(const float* __restrict__ X,
                                                      short* __restrict__ Y) {
  const int i = blockIdx.x * 256 + threadIdx.x;
  const float4* xv = reinterpret_cast<const float4*>(X);
  const float4 a = xv[(size_t)i * 2];
  const float4 b = xv[(size_t)i * 2 + 1];
  bf16x8 o;
  o[0] = f2bf(a.x); o[1] = f2bf(a.y); o[2] = f2bf(a.z); o[3] = f2bf(a.w);
  o[4] = f2bf(b.x); o[5] = f2bf(b.y); o[6] = f2bf(b.z); o[7] = f2bf(b.w);
  *reinterpret_cast<bf16x8*>(Y + (size_t)i * 8) = o;
}

// Fused scores+softmax. One block = 32-row stripe x all 2048 cols of one batch.
// 8 waves: wave w covers cols (jt*256 + w*32) per j-step. A-frags persistent in
// registers; B-frags streamed from L2 (X16 batch = 2MB, L2-resident); S stored
// as f16 in 128 KiB LDS; then one barrier + in-LDS row softmax + f32 writes.
// No barriers in the GEMM loop at all.
__global__ __launch_bounds__(512) void fused_kernel(const short* __restrict__ X16,
                                                    float* __restrict__ P) {
  const int b  = blockIdx.x & 7;           // batch pinned per XCD (perf heuristic)
  const int s0 = (blockIdx.x >> 3) * 32;   // stripe start row
  const short* Xb = X16 + (size_t)b * NTOK * DDIM;
  float* Pb = P + (size_t)b * NTOK * NTOK;

  __shared__ __half Sst[32][NTOK];         // 32*2048*2 = 128 KiB

  const int t    = threadIdx.x;
  const int lane = t & 63;
  const int w    = t >> 6;
  const int lr   = lane & 15;
  const int lk   = (lane >> 4) * 8;        // k sub-chunk (8 bf16)

  // ---- persistent A-frags: rows s0+m*16+lr, k = ks*32+lk  (2x16 frags, 128 VGPR)
  bf16x8 afrag[2][16];
#pragma unroll
  for (int m = 0; m < 2; ++m)
#pragma unroll
    for (int ks = 0; ks < 16; ++ks)
      afrag[m][ks] = *reinterpret_cast<const bf16x8*>(
          Xb + (size_t)(s0 + m * 16 + lr) * DDIM + ks * 32 + lk);

  const int crow = (lane >> 4) * 4;
  const int ccol = lane & 15;

  // ---- GEMM loop: 8 j-steps of 256 cols (wave w -> 32 cols)
  for (int jt = 0; jt < 8; ++jt) {
    const int c0 = jt * 256 + w * 32;      // this wave's col base
    f32x4 acc[2][2] = {};
#pragma unroll
    for (int ks = 0; ks < 16; ++ks) {
      const bf16x8 b0 = *reinterpret_cast<const bf16x8*>(
          Xb + (size_t)(c0 + lr) * DDIM + ks * 32 + lk);
      const bf16x8 b1 = *reinterpret_cast<const bf16x8*>(
          Xb + (size_t)(c0 + 16 + lr) * DDIM + ks * 32 + lk);
      acc[0][0] = __builtin_amdgcn_mfma_f32_16x16x32_bf16(afrag[0][ks], b0, acc[0][0], 0, 0, 0);
      acc[0][1] = __builtin_amdgcn_mfma_f32_16x16x32_bf16(afrag[0][ks], b1, acc[0][1], 0, 0, 0);
      acc[1][0] = __builtin_amdgcn_mfma_f32_16x16x32_bf16(afrag[1][ks], b0, acc[1][0], 0, 0, 0);
      acc[1][1] = __builtin_amdgcn_mfma_f32_16x16x32_bf16(afrag[1][ks], b1, acc[1][1], 0, 0, 0);
    }
    // dump S-subtile to LDS as f16 (C/D layout: col=lane&15, row=(lane>>4)*4+r)
#pragma unroll
    for (int m = 0; m < 2; ++m)
#pragma unroll
      for (int n = 0; n < 2; ++n)
#pragma unroll
        for (int r = 0; r < 4; ++r)
          Sst[m * 16 + crow + r][c0 + n * 16 + ccol] = f2h(acc[m][n][r]);
  }

  __syncthreads();

  // ---- row softmax from LDS; wave w owns rows w*4 .. w*4+3
#pragma unroll
  for (int rr = 0; rr < 4; ++rr) {
    const int row = w * 4 + rr;
    float v[32];
    // lane handles cols lane*4 + c*256, c = 0..7 (4 f16 per chunk, 8B reads)
#pragma unroll
    for (int c = 0; c < 8; ++c) {
      const short4 h = *reinterpret_cast<const short4*>(&Sst[row][lane * 4 + c * 256]);
      v[c * 4 + 0] = h2f(h.x);
      v[c * 4 + 1] = h2f(h.y);
      v[c * 4 + 2] = h2f(h.z);
      v[c * 4 + 3] = h2f(h.w);
    }
    float m = v[0];
#pragma unroll
    for (int k = 1; k < 32; ++k) m = fmaxf(m, v[k]);
#pragma unroll
    for (int off = 32; off > 0; off >>= 1) m = fmaxf(m, __shfl_xor(m, off));

    float s = 0.f;
#pragma unroll
    for (int k = 0; k < 32; ++k) { v[k] = __expf(v[k] - m); s += v[k]; }
#pragma unroll
    for (int off = 32; off > 0; off >>= 1) s += __shfl_xor(s, off);

    const float inv = 1.0f / s;
    float* outp = Pb + (size_t)(s0 + row) * NTOK;
#pragma unroll
    for (int c = 0; c < 8; ++c) {
      f32x4 o;
      o[0] = v[c * 4 + 0] * inv;
      o[1] = v[c * 4 + 1] * inv;
      o[2] = v[c * 4 + 2] * inv;
      o[3] = v[c * 4 + 3] * inv;
      *reinterpret_cast<f32x4*>(outp + lane * 4 + c * 256) = o;
    }
  }
}

// ---------- fallback path (ws too small): round-1 verified kernels ----------
__global__ __launch_bounds__(256) void scores_kernel(const float* __restrict__ X,
                                                     float* __restrict__ S) {
  const int b  = blockIdx.z;
  const int i0 = blockIdx.y * 128;
  const int j0 = blockIdx.x * 128;
  const float* Xb = X + (size_t)b * NTOK * DDIM;
  float* Sb = S + (size_t)b * NTOK * NTOK;

  __shared__ short lds_a[128][64];
  __shared__ short lds_b[128][64];

  const int t    = threadIdx.x;
  const int lane = t & 63;
  const int w    = t >> 6;
  const int wr   = (w >> 1) * 64;
  const int wc   = (w & 1) * 64;
  const int lr   = lane & 15;
  const int lk   = (lane >> 4) * 8;

  f32x4 acc[4][4] = {};

  for (int k0 = 0; k0 < DDIM; k0 += 64) {
#pragma unroll
    for (int q = 0; q < 8; ++q) {
      const int v  = t + 256 * q;
      const int r  = v >> 4;
      const int c4 = (v & 15) * 4;
      const float4 va = *reinterpret_cast<const float4*>(
          Xb + (size_t)(i0 + r) * DDIM + k0 + c4);
      const float4 vb = *reinterpret_cast<const float4*>(
          Xb + (size_t)(j0 + r) * DDIM + k0 + c4);
      short4 sa, sb;
      sa.x = f2bf(va.x); sa.y = f2bf(va.y); sa.z = f2bf(va.z); sa.w = f2bf(va.w);
      sb.x = f2bf(vb.x); sb.y = f2bf(vb.y); sb.z = f2bf(vb.z); sb.w = f2bf(vb.w);
      *reinterpret_cast<short4*>(&lds_a[r][c4]) = sa;
      *reinterpret_cast<short4*>(&lds_b[r][c4]) = sb;
    }
    __syncthreads();

#pragma unroll
    for (int ks = 0; ks < 2; ++ks) {
      bf16x8 af[4], bfr[4];
#pragma unroll
      for (int m = 0; m < 4; ++m)
        af[m] = *reinterpret_cast<const bf16x8*>(&lds_a[wr + m * 16 + lr][ks * 32 + lk]);
#pragma unroll
      for (int n = 0; n < 4; ++n)
        bfr[n] = *reinterpret_cast<const bf16x8*>(&lds_b[wc + n * 16 + lr][ks * 32 + lk]);
#pragma unroll
      for (int m = 0; m < 4; ++m)
#pragma unroll
        for (int n = 0; n < 4; ++n)
          acc[m][n] = __builtin_amdgcn_mfma_f32_16x16x32_bf16(af[m], bfr[n], acc[m][n], 0, 0, 0);
    }
    __syncthreads();
  }

  const int crow = (lane >> 4) * 4;
  const int ccol = lane & 15;
#pragma unroll
  for (int m = 0; m < 4; ++m) {
#pragma unroll
    for (int n = 0; n < 4; ++n) {
      const int gr = i0 + wr + m * 16 + crow;
      const int gc = j0 + wc + n * 16 + ccol;
      float* outp = Sb + (size_t)gr * NTOK + gc;
#pragma unroll
      for (int r = 0; r < 4; ++r)
        outp[(size_t)r * NTOK] = acc[m][n][r];
    }
  }
}

__global__ __launch_bounds__(256) void softmax_kernel(float* __restrict__ S) {
  float* row = S + (size_t)blockIdx.x * NTOK;
  const int t    = threadIdx.x;
  const int lane = t & 63;
  const int w    = t >> 6;

  float4* rv = reinterpret_cast<float4*>(row);
  float4 a = rv[t];
  float4 b = rv[t + 256];

  float m = fmaxf(fmaxf(fmaxf(a.x, a.y), fmaxf(a.z, a.w)),
                  fmaxf(fmaxf(b.x, b.y), fmaxf(b.z, b.w)));
#pragma unroll
  for (int off = 32; off > 0; off >>= 1) m = fmaxf(m, __shfl_xor(m, off));

  __shared__ float redm[4];
  __shared__ float reds[4];
  if (lane == 0) redm[w] = m;
  __syncthreads();
  m = fmaxf(fmaxf(redm[0], redm[1]), fmaxf(redm[2], redm[3]));

  a.x = __expf(a.x - m); a.y = __expf(a.y - m);
  a.z = __expf(a.z - m); a.w = __expf(a.w - m);
  b.x = __expf(b.x - m); b.y = __expf(b.y - m);
  b.z = __expf(b.z - m); b.w = __expf(b.w - m);

  float s = (a.x + a.y + a.z + a.w) + (b.x + b.y + b.z + b.w);
#pragma unroll
  for (int off = 32; off > 0; off >>= 1) s += __shfl_xor(s, off);
  if (lane == 0) reds[w] = s;
  __syncthreads();
  s = reds[0] + reds[1] + reds[2] + reds[3];

  const float inv = 1.0f / s;
  a.x *= inv; a.y *= inv; a.z *= inv; a.w *= inv;
  b.x *= inv; b.y *= inv; b.z *= inv; b.w *= inv;
  rv[t] = a;
  rv[t + 256] = b;
}

extern "C" void kernel_launch(void* const* d_in, const int* in_sizes, int n_in,
                              void* d_out, int out_size, void* d_ws, size_t ws_size,
                              hipStream_t stream) {
  const float* X = (const float*)d_in[0];
  float* out = (float*)d_out;

  const size_t need = (size_t)NBATCH * NTOK * DDIM * sizeof(short);  // 16.8 MB

  if (ws_size >= need) {
    short* Xb16 = (short*)d_ws;
    const int n_threads = NBATCH * NTOK * DDIM / 8;
    convert_kernel<<<n_threads / 256, 256, 0, stream>>>(X, Xb16);
    // 64 stripes/batch * 8 batches; batch = blockIdx&7 pins batch per XCD
    fused_kernel<<<NTOK / 32 * NBATCH, 512, 0, stream>>>(Xb16, out);
  } else {
    dim3 ggrid(NTOK / 128, NTOK / 128, NBATCH);
    scores_kernel<<<ggrid, 256, 0, stream>>>(X, out);
    softmax_kernel<<<NBATCH * NTOK, 256, 0, stream>>>(out);
  }
}

// Round 6
// 101.987 us; speedup vs baseline: 1.5514x; 1.5514x over previous
//
#include <hip/hip_runtime.h>
#include <hip/hip_bf16.h>

#define NTOK 2048
#define DDIM 512
#define NBATCH 8

using bf16x8 = __attribute__((ext_vector_type(8))) short;
using f32x4  = __attribute__((ext_vector_type(4))) float;

__device__ __forceinline__ short f2bf(float f) {
  __hip_bfloat16 h = __float2bfloat16(f);
  union { __hip_bfloat16 h; short s; } u; u.h = h;
  return u.s;
}

__device__ __forceinline__ void async_copy16(void* lds, const void* g) {
  __builtin_amdgcn_global_load_lds(
      (const __attribute__((address_space(1))) void*)g,
      (__attribute__((address_space(3))) void*)lds,
      16, 0, 0);
}

// fp32 -> bf16 pre-convert: each thread handles 8 floats -> one 16B bf16x8 store.
__global__ __launch_bounds__(256) void convert_kernel(const float* __restrict__ X,
                                                      short* __restrict__ Y) {
  const int i = blockIdx.x * 256 + threadIdx.x;
  const float4* xv = reinterpret_cast<const float4*>(X);
  const float4 a = xv[(size_t)i * 2];
  const float4 b = xv[(size_t)i * 2 + 1];
  bf16x8 o;
  o[0] = f2bf(a.x); o[1] = f2bf(a.y); o[2] = f2bf(a.z); o[3] = f2bf(a.w);
  o[4] = f2bf(b.x); o[5] = f2bf(b.y); o[6] = f2bf(b.z); o[7] = f2bf(b.w);
  *reinterpret_cast<bf16x8*>(Y + (size_t)i * 8) = o;
}

// Symmetric scores, 256x256 tile, 2-phase double-buffered staging.
// 512 thr / 8 waves (2M x 4N), wave tile 128x64, acc 8x4 f32x4.
// BK=64 -> 8 K-tiles; stage(t+1) issued BEFORE compute(t) so the
// __syncthreads() drain overlaps load latency with 64 MFMAs/wave.
// grid: 1D, bid&7 = batch (pins each batch's 2MB X to one XCD L2),
// bid>>3 = triangular tile index over the 8x8 tile grid.
__global__ __launch_bounds__(512, 2) void scores_sym256_kernel(
    const short* __restrict__ X16, float* __restrict__ S) {
  // triangular index -> (bi, bj), bi <= bj over 8x8 tiles
  int rem = blockIdx.x >> 3;
  int bi = 0;
  while (rem >= 8 - bi) { rem -= 8 - bi; ++bi; }
  const int bj = bi + rem;
  const int b  = blockIdx.x & 7;

  const int i0 = bi * 256;
  const int j0 = bj * 256;
  const short* Xb = X16 + (size_t)b * NTOK * DDIM;
  float* Sb = S + (size_t)b * NTOK * NTOK;

  __shared__ short lds_a[2][256 * 64];   // 32 KB each buf
  __shared__ short lds_b[2][256 * 64];   // total 128 KB

  const int t    = threadIdx.x;
  const int lane = t & 63;
  const int w    = t >> 6;               // 0..7
  const int wr   = (w >> 2) * 128;       // wave row offset (2 M-waves)
  const int wc   = (w & 3) * 64;         // wave col offset (4 N-waves)
  const int lr   = lane & 15;
  const int lk   = (lane >> 4) * 8;      // k sub-chunk (8 bf16)

  // staging: 32 segs of 1KB per operand; wave w stages segs w*4..w*4+3
  const int srow = lane >> 3;            // row within 8-row segment
  const int scb  = (lane & 7) * 16;      // byte col within 128-B row

  f32x4 acc[8][4] = {};

  auto stage = [&](int buf, int kt) {
    const int k0 = kt * 64;
#pragma unroll
    for (int q = 0; q < 4; ++q) {
      const int seg = w * 4 + q;          // wave-uniform
      const int row = seg * 8 + srow;     // per-lane
      async_copy16(&lds_a[buf][seg * 512],
                   (const char*)(Xb + (size_t)(i0 + row) * DDIM + k0) + scb);
      async_copy16(&lds_b[buf][seg * 512],
                   (const char*)(Xb + (size_t)(j0 + row) * DDIM + k0) + scb);
    }
  };

  auto compute = [&](int buf) {
#pragma unroll
    for (int ks = 0; ks < 2; ++ks) {
      bf16x8 af[8], bf[4];
#pragma unroll
      for (int m = 0; m < 8; ++m)
        af[m] = *reinterpret_cast<const bf16x8*>(
            &lds_a[buf][(wr + m * 16 + lr) * 64 + ks * 32 + lk]);
#pragma unroll
      for (int n = 0; n < 4; ++n)
        bf[n] = *reinterpret_cast<const bf16x8*>(
            &lds_b[buf][(wc + n * 16 + lr) * 64 + ks * 32 + lk]);
#pragma unroll
      for (int m = 0; m < 8; ++m)
#pragma unroll
        for (int n = 0; n < 4; ++n)
          acc[m][n] = __builtin_amdgcn_mfma_f32_16x16x32_bf16(af[m], bf[n], acc[m][n], 0, 0, 0);
    }
  };

  // prologue
  stage(0, 0);
  __syncthreads();

  int cur = 0;
  for (int kt = 0; kt < 7; ++kt) {
    stage(cur ^ 1, kt + 1);   // issue next-tile loads first
    compute(cur);             // 128 MFMAs/wave overlap the loads
    __syncthreads();          // drains vmcnt+lgkm, flips buffer safely
    cur ^= 1;
  }
  compute(cur);

  // ---- epilogue: C/D layout col = lane&15, row = (lane>>4)*4 + reg  [m89/m91]
  const int crow = (lane >> 4) * 4;
  const int ccol = lane & 15;
  const bool offdiag = (bi != bj);

#pragma unroll
  for (int m = 0; m < 8; ++m) {
#pragma unroll
    for (int n = 0; n < 4; ++n) {
      const int gr = i0 + wr + m * 16 + crow;
      const int gc = j0 + wc + n * 16 + ccol;
      float* outp = Sb + (size_t)gr * NTOK + gc;
#pragma unroll
      for (int r = 0; r < 4; ++r)
        outp[(size_t)r * NTOK] = acc[m][n][r];
      if (offdiag) {
        // mirror: rows gr..gr+3 at col gc -> one aligned f32x4 at [gc][gr]
        *reinterpret_cast<f32x4*>(Sb + (size_t)gc * NTOK + gr) = acc[m][n];
      }
    }
  }
}

// ---------- fallback path (ws too small): round-1 verified kernels ----------
__global__ __launch_bounds__(256) void scores_kernel(const float* __restrict__ X,
                                                     float* __restrict__ S) {
  const int b  = blockIdx.z;
  const int i0 = blockIdx.y * 128;
  const int j0 = blockIdx.x * 128;
  const float* Xb = X + (size_t)b * NTOK * DDIM;
  float* Sb = S + (size_t)b * NTOK * NTOK;

  __shared__ short lds_a[128][64];
  __shared__ short lds_b[128][64];

  const int t    = threadIdx.x;
  const int lane = t & 63;
  const int w    = t >> 6;
  const int wr   = (w >> 1) * 64;
  const int wc   = (w & 1) * 64;
  const int lr   = lane & 15;
  const int lk   = (lane >> 4) * 8;

  f32x4 acc[4][4] = {};

  for (int k0 = 0; k0 < DDIM; k0 += 64) {
#pragma unroll
    for (int q = 0; q < 8; ++q) {
      const int v  = t + 256 * q;
      const int r  = v >> 4;
      const int c4 = (v & 15) * 4;
      const float4 va = *reinterpret_cast<const float4*>(
          Xb + (size_t)(i0 + r) * DDIM + k0 + c4);
      const float4 vb = *reinterpret_cast<const float4*>(
          Xb + (size_t)(j0 + r) * DDIM + k0 + c4);
      short4 sa, sb;
      sa.x = f2bf(va.x); sa.y = f2bf(va.y); sa.z = f2bf(va.z); sa.w = f2bf(va.w);
      sb.x = f2bf(vb.x); sb.y = f2bf(vb.y); sb.z = f2bf(vb.z); sb.w = f2bf(vb.w);
      *reinterpret_cast<short4*>(&lds_a[r][c4]) = sa;
      *reinterpret_cast<short4*>(&lds_b[r][c4]) = sb;
    }
    __syncthreads();

#pragma unroll
    for (int ks = 0; ks < 2; ++ks) {
      bf16x8 af[4], bfr[4];
#pragma unroll
      for (int m = 0; m < 4; ++m)
        af[m] = *reinterpret_cast<const bf16x8*>(&lds_a[wr + m * 16 + lr][ks * 32 + lk]);
#pragma unroll
      for (int n = 0; n < 4; ++n)
        bfr[n] = *reinterpret_cast<const bf16x8*>(&lds_b[wc + n * 16 + lr][ks * 32 + lk]);
#pragma unroll
      for (int m = 0; m < 4; ++m)
#pragma unroll
        for (int n = 0; n < 4; ++n)
          acc[m][n] = __builtin_amdgcn_mfma_f32_16x16x32_bf16(af[m], bfr[n], acc[m][n], 0, 0, 0);
    }
    __syncthreads();
  }

  const int crow = (lane >> 4) * 4;
  const int ccol = lane & 15;
#pragma unroll
  for (int m = 0; m < 4; ++m) {
#pragma unroll
    for (int n = 0; n < 4; ++n) {
      const int gr = i0 + wr + m * 16 + crow;
      const int gc = j0 + wc + n * 16 + ccol;
      float* outp = Sb + (size_t)gr * NTOK + gc;
#pragma unroll
      for (int r = 0; r < 4; ++r)
        outp[(size_t)r * NTOK] = acc[m][n][r];
    }
  }
}

// In-place row softmax: one 256-thread block per row of 2048 fp32.
__global__ __launch_bounds__(256) void softmax_kernel(float* __restrict__ S) {
  float* row = S + (size_t)blockIdx.x * NTOK;
  const int t    = threadIdx.x;
  const int lane = t & 63;
  const int w    = t >> 6;

  float4* rv = reinterpret_cast<float4*>(row);
  float4 a = rv[t];
  float4 b = rv[t + 256];

  float m = fmaxf(fmaxf(fmaxf(a.x, a.y), fmaxf(a.z, a.w)),
                  fmaxf(fmaxf(b.x, b.y), fmaxf(b.z, b.w)));
#pragma unroll
  for (int off = 32; off > 0; off >>= 1) m = fmaxf(m, __shfl_xor(m, off));

  __shared__ float redm[4];
  __shared__ float reds[4];
  if (lane == 0) redm[w] = m;
  __syncthreads();
  m = fmaxf(fmaxf(redm[0], redm[1]), fmaxf(redm[2], redm[3]));

  a.x = __expf(a.x - m); a.y = __expf(a.y - m);
  a.z = __expf(a.z - m); a.w = __expf(a.w - m);
  b.x = __expf(b.x - m); b.y = __expf(b.y - m);
  b.z = __expf(b.z - m); b.w = __expf(b.w - m);

  float s = (a.x + a.y + a.z + a.w) + (b.x + b.y + b.z + b.w);
#pragma unroll
  for (int off = 32; off > 0; off >>= 1) s += __shfl_xor(s, off);
  if (lane == 0) reds[w] = s;
  __syncthreads();
  s = reds[0] + reds[1] + reds[2] + reds[3];

  const float inv = 1.0f / s;
  a.x *= inv; a.y *= inv; a.z *= inv; a.w *= inv;
  b.x *= inv; b.y *= inv; b.z *= inv; b.w *= inv;
  rv[t] = a;
  rv[t + 256] = b;
}

extern "C" void kernel_launch(void* const* d_in, const int* in_sizes, int n_in,
                              void* d_out, int out_size, void* d_ws, size_t ws_size,
                              hipStream_t stream) {
  const float* X = (const float*)d_in[0];
  float* out = (float*)d_out;

  const size_t need = (size_t)NBATCH * NTOK * DDIM * sizeof(short);  // 16.8 MB

  if (ws_size >= need) {
    short* Xb16 = (short*)d_ws;
    const int n_threads = NBATCH * NTOK * DDIM / 8;
    convert_kernel<<<n_threads / 256, 256, 0, stream>>>(X, Xb16);
    // 36 triangular 256x256 tiles x 8 batches; bid&7 = batch (XCD pin)
    scores_sym256_kernel<<<36 * NBATCH, 512, 0, stream>>>(Xb16, out);
  } else {
    dim3 ggrid(NTOK / 128, NTOK / 128, NBATCH);
    scores_kernel<<<ggrid, 256, 0, stream>>>(X, out);
  }
  softmax_kernel<<<NBATCH * NTOK, 256, 0, stream>>>(out);
}

// Round 7
// 97.264 us; speedup vs baseline: 1.6267x; 1.0486x over previous
//
#include <hip/hip_runtime.h>
#include <hip/hip_bf16.h>

#define NTOK 2048
#define DDIM 512
#define NBATCH 8

using bf16x8 = __attribute__((ext_vector_type(8))) short;
using f32x4  = __attribute__((ext_vector_type(4))) float;

__device__ __forceinline__ short f2bf(float f) {
  __hip_bfloat16 h = __float2bfloat16(f);
  union { __hip_bfloat16 h; short s; } u; u.h = h;
  return u.s;
}

__device__ __forceinline__ void async_copy16(void* lds, const void* g) {
  __builtin_amdgcn_global_load_lds(
      (const __attribute__((address_space(1))) void*)g,
      (__attribute__((address_space(3))) void*)lds,
      16, 0, 0);
}

// fp32 -> bf16 pre-convert: each thread handles 8 floats -> one 16B bf16x8 store.
__global__ __launch_bounds__(256) void convert_kernel(const float* __restrict__ X,
                                                      short* __restrict__ Y) {
  const int i = blockIdx.x * 256 + threadIdx.x;
  const float4* xv = reinterpret_cast<const float4*>(X);
  const float4 a = xv[(size_t)i * 2];
  const float4 b = xv[(size_t)i * 2 + 1];
  bf16x8 o;
  o[0] = f2bf(a.x); o[1] = f2bf(a.y); o[2] = f2bf(a.z); o[3] = f2bf(a.w);
  o[4] = f2bf(b.x); o[5] = f2bf(b.y); o[6] = f2bf(b.z); o[7] = f2bf(b.w);
  *reinterpret_cast<bf16x8*>(Y + (size_t)i * 8) = o;
}

// Symmetric scores, 256x256 tile, BK=32 double-buffered (64 KiB LDS ->
// 2 blocks/CU, all 288 blocks co-resident). 512 thr / 8 waves (2M x 4N),
// wave tile 128x64, acc 8x4 f32x4. 16 K-steps; stage(t+1) issued BEFORE
// compute(t); one __syncthreads per K-step. Diagonal blocks alias B->A
// (identical data) and skip B staging.
__global__ __launch_bounds__(512, 2) void scores_sym256_kernel(
    const short* __restrict__ X16, float* __restrict__ S) {
  // triangular index -> (bi, bj), bi <= bj over 8x8 tiles of 256
  int rem = blockIdx.x >> 3;
  int bi = 0;
  while (rem >= 8 - bi) { rem -= 8 - bi; ++bi; }
  const int bj = bi + rem;
  const int b  = blockIdx.x & 7;           // batch -> XCD pin (perf heuristic)
  const bool diag = (bi == bj);

  const int i0 = bi * 256;
  const int j0 = bj * 256;
  const short* Xb = X16 + (size_t)b * NTOK * DDIM;
  float* Sb = S + (size_t)b * NTOK * NTOK;

  __shared__ short lds_a[2][256 * 32];     // 16 KB per buf
  __shared__ short lds_b[2][256 * 32];     // total 64 KB

  const int t    = threadIdx.x;
  const int lane = t & 63;
  const int w    = t >> 6;                 // 0..7
  const int wr   = (w >> 2) * 128;         // wave row offset (2 M-waves)
  const int wc   = (w & 3) * 64;           // wave col offset (4 N-waves)
  const int lr   = lane & 15;
  const int lk2  = (lane >> 4) * 8;        // k sub-chunk (8 bf16 of 32)

  // staging: per operand 16 segs of 1 KB (16 rows x 64 B); wave w stages
  // segs w*2, w*2+1. Lane -> row seg*16 + (lane>>2), byte col (lane&3)*16.
  const int srow = lane >> 2;
  const int scb  = (lane & 3) * 16;

  f32x4 acc[8][4] = {};

  auto stage = [&](int buf, int kt) {
    const int k0 = kt * 32;
#pragma unroll
    for (int q = 0; q < 2; ++q) {
      const int seg = w * 2 + q;            // wave-uniform
      const int row = seg * 16 + srow;      // per-lane
      async_copy16(&lds_a[buf][seg * 512],
                   (const char*)(Xb + (size_t)(i0 + row) * DDIM + k0) + scb);
      if (!diag)
        async_copy16(&lds_b[buf][seg * 512],
                     (const char*)(Xb + (size_t)(j0 + row) * DDIM + k0) + scb);
    }
  };

  auto compute = [&](int buf) {
    const short* A0 = lds_a[buf];
    const short* B0 = diag ? lds_a[buf] : lds_b[buf];
    bf16x8 af[8], bfr[4];
#pragma unroll
    for (int m = 0; m < 8; ++m)
      af[m] = *reinterpret_cast<const bf16x8*>(&A0[(wr + m * 16 + lr) * 32 + lk2]);
#pragma unroll
    for (int n = 0; n < 4; ++n)
      bfr[n] = *reinterpret_cast<const bf16x8*>(&B0[(wc + n * 16 + lr) * 32 + lk2]);
#pragma unroll
    for (int m = 0; m < 8; ++m)
#pragma unroll
      for (int n = 0; n < 4; ++n)
        acc[m][n] = __builtin_amdgcn_mfma_f32_16x16x32_bf16(af[m], bfr[n], acc[m][n], 0, 0, 0);
  };

  // prologue
  stage(0, 0);
  __syncthreads();

  int cur = 0;
#pragma unroll 4
  for (int kt = 0; kt < 15; ++kt) {
    stage(cur ^ 1, kt + 1);   // issue next-tile loads first
    compute(cur);             // 32 MFMAs/wave overlap the loads
    __syncthreads();          // drains vmcnt+lgkm, flips buffer safely
    cur ^= 1;
  }
  compute(cur);

  // ---- epilogue: C/D layout col = lane&15, row = (lane>>4)*4 + reg  [m89/m91]
  const int crow = (lane >> 4) * 4;
  const int ccol = lane & 15;

#pragma unroll
  for (int m = 0; m < 8; ++m) {
#pragma unroll
    for (int n = 0; n < 4; ++n) {
      const int gr = i0 + wr + m * 16 + crow;
      const int gc = j0 + wc + n * 16 + ccol;
      float* outp = Sb + (size_t)gr * NTOK + gc;
#pragma unroll
      for (int r = 0; r < 4; ++r)
        outp[(size_t)r * NTOK] = acc[m][n][r];
      if (!diag) {
        // mirror: rows gr..gr+3 at col gc -> one aligned f32x4 at [gc][gr]
        *reinterpret_cast<f32x4*>(Sb + (size_t)gc * NTOK + gr) = acc[m][n];
      }
    }
  }
}

// ---------- fallback path (ws too small): round-1 verified kernels ----------
__global__ __launch_bounds__(256) void scores_kernel(const float* __restrict__ X,
                                                     float* __restrict__ S) {
  const int b  = blockIdx.z;
  const int i0 = blockIdx.y * 128;
  const int j0 = blockIdx.x * 128;
  const float* Xb = X + (size_t)b * NTOK * DDIM;
  float* Sb = S + (size_t)b * NTOK * NTOK;

  __shared__ short lds_a[128][64];
  __shared__ short lds_b[128][64];

  const int t    = threadIdx.x;
  const int lane = t & 63;
  const int w    = t >> 6;
  const int wr   = (w >> 1) * 64;
  const int wc   = (w & 1) * 64;
  const int lr   = lane & 15;
  const int lk   = (lane >> 4) * 8;

  f32x4 acc[4][4] = {};

  for (int k0 = 0; k0 < DDIM; k0 += 64) {
#pragma unroll
    for (int q = 0; q < 8; ++q) {
      const int v  = t + 256 * q;
      const int r  = v >> 4;
      const int c4 = (v & 15) * 4;
      const float4 va = *reinterpret_cast<const float4*>(
          Xb + (size_t)(i0 + r) * DDIM + k0 + c4);
      const float4 vb = *reinterpret_cast<const float4*>(
          Xb + (size_t)(j0 + r) * DDIM + k0 + c4);
      short4 sa, sb;
      sa.x = f2bf(va.x); sa.y = f2bf(va.y); sa.z = f2bf(va.z); sa.w = f2bf(va.w);
      sb.x = f2bf(vb.x); sb.y = f2bf(vb.y); sb.z = f2bf(vb.z); sb.w = f2bf(vb.w);
      *reinterpret_cast<short4*>(&lds_a[r][c4]) = sa;
      *reinterpret_cast<short4*>(&lds_b[r][c4]) = sb;
    }
    __syncthreads();

#pragma unroll
    for (int ks = 0; ks < 2; ++ks) {
      bf16x8 af[4], bfr[4];
#pragma unroll
      for (int m = 0; m < 4; ++m)
        af[m] = *reinterpret_cast<const bf16x8*>(&lds_a[wr + m * 16 + lr][ks * 32 + lk]);
#pragma unroll
      for (int n = 0; n < 4; ++n)
        bfr[n] = *reinterpret_cast<const bf16x8*>(&lds_b[wc + n * 16 + lr][ks * 32 + lk]);
#pragma unroll
      for (int m = 0; m < 4; ++m)
#pragma unroll
        for (int n = 0; n < 4; ++n)
          acc[m][n] = __builtin_amdgcn_mfma_f32_16x16x32_bf16(af[m], bfr[n], acc[m][n], 0, 0, 0);
    }
    __syncthreads();
  }

  const int crow = (lane >> 4) * 4;
  const int ccol = lane & 15;
#pragma unroll
  for (int m = 0; m < 4; ++m) {
#pragma unroll
    for (int n = 0; n < 4; ++n) {
      const int gr = i0 + wr + m * 16 + crow;
      const int gc = j0 + wc + n * 16 + ccol;
      float* outp = Sb + (size_t)gr * NTOK + gc;
#pragma unroll
      for (int r = 0; r < 4; ++r)
        outp[(size_t)r * NTOK] = acc[m][n][r];
    }
  }
}

// In-place row softmax: one 256-thread block per row of 2048 fp32.
__global__ __launch_bounds__(256) void softmax_kernel(float* __restrict__ S) {
  float* row = S + (size_t)blockIdx.x * NTOK;
  const int t    = threadIdx.x;
  const int lane = t & 63;
  const int w    = t >> 6;

  float4* rv = reinterpret_cast<float4*>(row);
  float4 a = rv[t];
  float4 b = rv[t + 256];

  float m = fmaxf(fmaxf(fmaxf(a.x, a.y), fmaxf(a.z, a.w)),
                  fmaxf(fmaxf(b.x, b.y), fmaxf(b.z, b.w)));
#pragma unroll
  for (int off = 32; off > 0; off >>= 1) m = fmaxf(m, __shfl_xor(m, off));

  __shared__ float redm[4];
  __shared__ float reds[4];
  if (lane == 0) redm[w] = m;
  __syncthreads();
  m = fmaxf(fmaxf(redm[0], redm[1]), fmaxf(redm[2], redm[3]));

  a.x = __expf(a.x - m); a.y = __expf(a.y - m);
  a.z = __expf(a.z - m); a.w = __expf(a.w - m);
  b.x = __expf(b.x - m); b.y = __expf(b.y - m);
  b.z = __expf(b.z - m); b.w = __expf(b.w - m);

  float s = (a.x + a.y + a.z + a.w) + (b.x + b.y + b.z + b.w);
#pragma unroll
  for (int off = 32; off > 0; off >>= 1) s += __shfl_xor(s, off);
  if (lane == 0) reds[w] = s;
  __syncthreads();
  s = reds[0] + reds[1] + reds[2] + reds[3];

  const float inv = 1.0f / s;
  a.x *= inv; a.y *= inv; a.z *= inv; a.w *= inv;
  b.x *= inv; b.y *= inv; b.z *= inv; b.w *= inv;
  rv[t] = a;
  rv[t + 256] = b;
}

extern "C" void kernel_launch(void* const* d_in, const int* in_sizes, int n_in,
                              void* d_out, int out_size, void* d_ws, size_t ws_size,
                              hipStream_t stream) {
  const float* X = (const float*)d_in[0];
  float* out = (float*)d_out;

  const size_t need = (size_t)NBATCH * NTOK * DDIM * sizeof(short);  // 16.8 MB

  if (ws_size >= need) {
    short* Xb16 = (short*)d_ws;
    const int n_threads = NBATCH * NTOK * DDIM / 8;
    convert_kernel<<<n_threads / 256, 256, 0, stream>>>(X, Xb16);
    // 36 triangular 256x256 tiles x 8 batches; bid&7 = batch (XCD pin)
    scores_sym256_kernel<<<36 * NBATCH, 512, 0, stream>>>(Xb16, out);
  } else {
    dim3 ggrid(NTOK / 128, NTOK / 128, NBATCH);
    scores_kernel<<<ggrid, 256, 0, stream>>>(X, out);
  }
  softmax_kernel<<<NBATCH * NTOK, 256, 0, stream>>>(out);
}